// Round 12
// baseline (681.766 us; speedup 1.0000x reference)
//
#include <hip/hip_runtime.h>

#define FLTMAX 3.402823466e+38f

// ---------------------------------------------------------------------------
// Geometry:
//   Layer1: B=1024, N=784, Np=896, S=7, F=512, I=8, K=4
//   Layer2: B=1024, N=512, Np=512, S=4, F=10,  I=8, K=4
// Layer-1: persistent-grid kernel, 1024 blocks x 256 threads, ONE 128x128
// tile per block (R0 geometry), 4 blocks/CU co-resident:
//   - LDS 34.4KB/block x4 = 137KB <= 160KB
//   - VGPR <=128 x (4 waves/SIMD from 4 blocks) = 512/SIMD
//   - amdgpu_waves_per_eu(4,4) pins the allocator: R4-R7's spill at
//     (256,4) was the compiler targeting 8 waves/SIMD (reported VGPR 64 +
//     ~64 regs scratch); min=max=4 lets it use the full 128-reg budget.
//
// R11 post-mortem: VALU-busy is ~380us across R9/R10/R11 (different
// codegen, same 2 blocks/CU) vs R0's GEMM at 4 blocks/CU hitting the VALU
// floor. Independent-block count per CU is the lever, not instruction
// mix. Also reverted: prefetch-across-barrier (R11: FETCH 45->83MB,
// WRITE 130->280MB, zero dur gain).
//
// Ordering chain (R5-R11, passed): tid0 issues device-scope atomicMin/Max
// on stats; s_waitcnt vmcnt(0) drains them to the coherence point; THEN
// arrival fetch_add on the slot counter. Waiters spin (RELAXED AGENT) and
// read stats with RELAXED AGENT loads — both at the coherence point past
// the non-coherent per-XCD L2. No fences (R3: fences = L2 flush storms).
// Pidx layout (R7): tile-major, tile = ((s*8+i)*16+colgrp)*8+btile, 16KB
// contiguous per tile; LDS-staged 16B stores (R5). fold1 unchanged.
// ---------------------------------------------------------------------------

// slotbar: 224 counters, one per (s*8+i)*4+k, 64B apart (16 words).
__device__ __forceinline__ void slot_barrier(unsigned* ctr, unsigned target)
{
    __syncthreads();
    if (threadIdx.x == 0) {
        // drain this wave's outstanding VMEM (incl. the stats atomics) so
        // they are complete at the coherence point before we signal.
        asm volatile("s_waitcnt vmcnt(0)" ::: "memory");
        __hip_atomic_fetch_add(ctr, 1u, __ATOMIC_RELAXED, __HIP_MEMORY_SCOPE_AGENT);
        // bounded spin (fails visibly, never hangs): healthy wait << 50us
        for (int it = 0; it < (1 << 22); ++it) {
            if (__hip_atomic_load(ctr, __ATOMIC_RELAXED, __HIP_MEMORY_SCOPE_AGENT) >= target)
                break;
            __builtin_amdgcn_s_sleep(2);
        }
    }
    __syncthreads();
}

// Fused: xq codes (row in LDS) -> sx1 row sum + bit-packed planes xqbT[i][w][b].
// Also initializes stats1 + slot-barrier counters.
__global__ void prep1_kernel(const float* __restrict__ x, float* __restrict__ sx1,
                             unsigned* __restrict__ xqbT, unsigned* __restrict__ stats1,
                             unsigned* __restrict__ bar)
{
    __shared__ float xr[896];
    __shared__ float red[128];
    int b = blockIdx.x;
    if (b == 0) {
        for (int t = threadIdx.x; t < 224; t += 128) {
            stats1[t * 2] = 0x7F7FFFFFu; stats1[t * 2 + 1] = 0u;
        }
        for (int t = threadIdx.x; t < 3584; t += 128) bar[t] = 0u;
    }
    float psum = 0.f;
    for (int n = threadIdx.x; n < 896; n += 128) {
        float v = 0.f;
        if (n < 784) {
            float xv = x[b * 784 + n];
            xv = fminf(fmaxf(xv, 0.f), 1.f);
            v = rintf(__fmul_rn(xv, 255.f));
        }
        xr[n] = v;
        psum += v;  // integer-valued, exact in any order
    }
    red[threadIdx.x] = psum;
    __syncthreads();
    for (int w = 64; w >= 1; w >>= 1) {
        if (threadIdx.x < w) red[threadIdx.x] += red[threadIdx.x + w];
        __syncthreads();
    }
    if (threadIdx.x == 0) sx1[b] = red[0];
    if (threadIdx.x < 28) {
        int w = threadIdx.x;
        unsigned words[8] = {0, 0, 0, 0, 0, 0, 0, 0};
#pragma unroll 8
        for (int n = 0; n < 32; ++n) {
            int v = (int)xr[w * 32 + n];
#pragma unroll
            for (int i = 0; i < 8; ++i) words[i] |= ((unsigned)((v >> i) & 1)) << n;
        }
#pragma unroll
        for (int i = 0; i < 8; ++i) xqbT[(i * 28 + w) * 1024 + b] = words[i];
    }
}

// Fused conductance-prep + transpose: writes g1t[n][k*512+f] directly.
__global__ void prepg1t_kernel(const float* __restrict__ w1, const float* __restrict__ noise1,
                               float* __restrict__ g1t)
{
    __shared__ float t[4][32][33];
    const int n0 = blockIdx.x * 32, f0 = blockIdx.y * 32;
    const int tid = threadIdx.x;
    {
        int n = tid & 31, fi = tid >> 5;
#pragma unroll
        for (int p = 0; p < 4; ++p) {
            int f = p * 8 + fi;
            int gn = n0 + n, gf = f0 + f;
            float gv[4] = {0.f, 0.f, 0.f, 0.f};
            if (gn < 784) {
                float w = w1[gf * 784 + gn];
                float Xi = fminf(fmaxf(rintf(__fmul_rn(__fmul_rn(__fadd_rn(w, 1.f), 0.5f), 255.f)),
                                       0.f), 255.f);
                int xi = (int)Xi;
                float4 nz = *(const float4*)&noise1[(gf * 896 + gn) * 4];
                float nzv[4] = {nz.x, nz.y, nz.z, nz.w};
#pragma unroll
                for (int k = 0; k < 4; ++k) {
                    int slc = (xi >> (2 * k)) & 3;
                    float base = __fadd_rn(__fmul_rn((float)slc, 0.9f), 0.3f);
                    float nf = __fadd_rn(1.f, __fmul_rn(0.05f, nzv[k]));
                    gv[k] = __fmul_rn(base, nf);
                }
            }
#pragma unroll
            for (int k = 0; k < 4; ++k) t[k][n][f] = gv[k];
        }
    }
    __syncthreads();
    {
        int f = tid & 31, nn = tid >> 5;
#pragma unroll
        for (int p = 0; p < 4; ++p) {
            int n = p * 8 + nn;
#pragma unroll
            for (int k = 0; k < 4; ++k)
                g1t[(n0 + n) * 2048 + k * 512 + f0 + f] = t[k][n][f];
        }
    }
}

// g2t[n][k][f] layout for layer-2 matmul
__global__ void prepg2_kernel(const float* __restrict__ w3, const float* __restrict__ noise3,
                              float* __restrict__ g2t)
{
    int gid = blockIdx.x * 256 + threadIdx.x;
    if (gid >= 10 * 512) return;
    int f = gid / 512, n = gid % 512;
    float w = w3[f * 512 + n];
    float Xi = fminf(fmaxf(rintf(__fmul_rn(__fmul_rn(__fadd_rn(w, 1.f), 0.5f), 255.f)),
                           0.f), 255.f);
    int xi = (int)Xi;
#pragma unroll
    for (int k = 0; k < 4; ++k) {
        int slc = (xi >> (2 * k)) & 3;
        float base = __fadd_rn(__fmul_rn((float)slc, 0.9f), 0.3f);
        float nf = __fadd_rn(1.f, __fmul_rn(0.05f, noise3[(f * 512 + n) * 4 + k]));
        g2t[n * 40 + k * 10 + f] = __fmul_rn(base, nf);
    }
}

// Layer-1 dummy column from transposed bit-planes: D = 0.3*popc(128 bits).
__global__ void dqpopT_kernel(const unsigned* __restrict__ xqbT, float* __restrict__ Dq)
{
    __shared__ float red[512];
    const int i = blockIdx.x / 7, s = blockIdx.x % 7;
    const int tid = threadIdx.x;
    float D[4];
    float mn = FLTMAX, mx = -FLTMAX;
#pragma unroll
    for (int u = 0; u < 4; ++u) {
        int b = tid + u * 256;
        int c = 0;
#pragma unroll
        for (int w = 0; w < 4; ++w)
            c += __popc(xqbT[(i * 28 + s * 4 + w) * 1024 + b]);
        D[u] = __fmul_rn((float)c, 0.3f);
        mn = fminf(mn, D[u]);
        mx = fmaxf(mx, D[u]);
    }
    red[tid] = mn; red[256 + tid] = mx;
    __syncthreads();
    for (int w = 128; w >= 1; w >>= 1) {
        if (tid < w) {
            red[tid] = fminf(red[tid], red[tid + w]);
            red[256 + tid] = fmaxf(red[256 + tid], red[256 + tid + w]);
        }
        __syncthreads();
    }
    mn = red[0]; mx = red[256];
    float step = __fmul_rn(__fsub_rn(mx, mn), 0.03125f);
    if (step <= 0.f) step = 1.f;
#pragma unroll
    for (int u = 0; u < 4; ++u) {
        int b = tid + u * 256;
        float idx = fminf(fmaxf(floorf(__fdiv_rn(__fsub_rn(D[u], mn), step)), 0.f), 31.f);
        Dq[(i * 7 + s) * 1024 + b] = __fadd_rn(__fmul_rn(idx, step), mn);
    }
}

// Layer-2 dummy column from xqb2 ([i][b][16w] layout).
__global__ void dqpop_kernel(const unsigned* __restrict__ xqb, float* __restrict__ Dq,
                             int S, int wpr)
{
    __shared__ float red[512];
    const int i = blockIdx.x / S, s = blockIdx.x % S;
    const int tid = threadIdx.x;
    float D[4];
    float mn = FLTMAX, mx = -FLTMAX;
#pragma unroll
    for (int u = 0; u < 4; ++u) {
        int b = tid + u * 256;
        uint4 w = *(const uint4*)&xqb[(i * 1024 + b) * wpr + s * 4];
        int c = __popc(w.x) + __popc(w.y) + __popc(w.z) + __popc(w.w);
        D[u] = __fmul_rn((float)c, 0.3f);
        mn = fminf(mn, D[u]);
        mx = fmaxf(mx, D[u]);
    }
    red[tid] = mn; red[256 + tid] = mx;
    __syncthreads();
    for (int w = 128; w >= 1; w >>= 1) {
        if (tid < w) {
            red[tid] = fminf(red[tid], red[tid + w]);
            red[256 + tid] = fmaxf(red[256 + tid], red[256 + tid + w]);
        }
        __syncthreads();
    }
    mn = red[0]; mx = red[256];
    float step = __fmul_rn(__fsub_rn(mx, mn), 0.03125f);
    if (step <= 0.f) step = 1.f;
#pragma unroll
    for (int u = 0; u < 4; ++u) {
        int b = tid + u * 256;
        float idx = fminf(fmaxf(floorf(__fdiv_rn(__fsub_rn(D[u], mn), step)), 0.f), 31.f);
        Dq[(i * S + s) * 1024 + b] = __fadd_rn(__fmul_rn(idx, step), mn);
    }
}

// ---------------------------------------------------------------------------
// Layer-1 persistent GEMM: 1024 blocks x 256 threads, 4 blocks/CU.
// One 128x128 tile per block (R0 geometry); scalar acc[8][8]; wave-shfl
// min/max; per-slot 32-block sync; within-plane prefetch only; tile-major
// Pidx with 16KB contiguous burst per block-plane.
// ---------------------------------------------------------------------------
#define BK 32
__global__ __launch_bounds__(256)
__attribute__((amdgpu_waves_per_eu(4, 4)))
void mm1_kernel(
    const unsigned* __restrict__ xqbT, const float* __restrict__ g1t,
    unsigned char* __restrict__ Pidx, unsigned* stats, unsigned* bar)
{
    __shared__ __align__(16) float Bs[BK][132];
    __shared__ unsigned Abits[128];
    __shared__ float redmn[4], redmx[4];
    __shared__ __align__(16) unsigned stage[128 * 33];
    const int tid = threadIdx.x;
    const int r = blockIdx.x & 63;
    const int i = r >> 3;
    const int btile = r & 7;
    const int b0 = btile * 128;
    const int colgrp = blockIdx.x >> 6;      // 0..15
    const int colBase = colgrp * 128;
    const int tx = tid & 15, ty = tid >> 4;
    const int aB = tid >> 5;          // 0..7  (B rows: u*8 + aB)
    const int eB = (tid & 31) << 2;   // 0..124
    const int k = colgrp >> 2;
    const int wv = tid >> 6, ln = tid & 63;

    for (int s = 0; s < 7; ++s) {
        // prefetch chunk 0  (xqbT layout: [i][w][b], w = s*4 + chunk)
        float4 pB[4];
        unsigned pAw = 0;
#pragma unroll
        for (int u = 0; u < 4; ++u)
            pB[u] = *(const float4*)&g1t[(s * 128 + u * 8 + aB) * 2048 + colBase + eB];
        if (tid < 128) pAw = xqbT[(i * 28 + s * 4) * 1024 + b0 + tid];

        float acc[8][8] = {};

        for (int ac = 0; ac < 4; ++ac) {
            __syncthreads();
#pragma unroll
            for (int u = 0; u < 4; ++u)
                *(float4*)&Bs[u * 8 + aB][eB] = pB[u];
            if (tid < 128) Abits[tid] = pAw;
            __syncthreads();

            if (ac < 3) {
                const int n0 = s * 128 + (ac + 1) * BK;
#pragma unroll
                for (int u = 0; u < 4; ++u)
                    pB[u] = *(const float4*)&g1t[(n0 + u * 8 + aB) * 2048 + colBase + eB];
                if (tid < 128) pAw = xqbT[(i * 28 + s * 4 + ac + 1) * 1024 + b0 + tid];
            }

            unsigned wrd[8];
#pragma unroll
            for (int u = 0; u < 4; ++u) {
                wrd[u]     = Abits[(ty << 2) + u];
                wrd[4 + u] = Abits[64 + (ty << 2) + u];
            }

#pragma unroll 4
            for (int a = 0; a < BK; ++a) {
                float br[8];
                *(float4*)&br[0] = *(const float4*)&Bs[a][(tx << 2)];
                *(float4*)&br[4] = *(const float4*)&Bs[a][64 + (tx << 2)];
#pragma unroll
                for (int u = 0; u < 8; ++u) {
                    float ab = (float)((wrd[u] >> a) & 1u);
#pragma unroll
                    for (int v = 0; v < 8; ++v)
                        acc[u][v] = fmaf(ab, br[v], acc[u][v]);
                }
            }
        }

        // min/max: wave shfl butterfly (no syncthreads), then one
        // cross-wave step. Order-independent -> bit-safe.
        float mn = acc[0][0], mx = acc[0][0];
#pragma unroll
        for (int u = 0; u < 8; ++u)
#pragma unroll
            for (int v = 0; v < 8; ++v) {
                mn = fminf(mn, acc[u][v]); mx = fmaxf(mx, acc[u][v]);
            }
#pragma unroll
        for (int o = 32; o >= 1; o >>= 1) {
            mn = fminf(mn, __shfl_xor(mn, o));
            mx = fmaxf(mx, __shfl_xor(mx, o));
        }
        if (ln == 0) { redmn[wv] = mn; redmx[wv] = mx; }
        __syncthreads();
        const int slot = ((s * 8 + i) * 4 + k);
        if (tid == 0) {
            float m0 = fminf(fminf(redmn[0], redmn[1]), fminf(redmn[2], redmn[3]));
            float m1 = fmaxf(fmaxf(redmx[0], redmx[1]), fmaxf(redmx[2], redmx[3]));
            atomicMin(&stats[slot * 2],     __float_as_uint(m0));
            atomicMax(&stats[slot * 2 + 1], __float_as_uint(m1));
        }

        // per-slot sync: the 32 blocks sharing (s,i,k) rendezvous.
        slot_barrier(&bar[slot * 16], 32u);

        // COHERENT read at the atomics' coherence point.
        unsigned mnu = __hip_atomic_load(&stats[slot * 2],     __ATOMIC_RELAXED,
                                         __HIP_MEMORY_SCOPE_AGENT);
        unsigned mxu = __hip_atomic_load(&stats[slot * 2 + 1], __ATOMIC_RELAXED,
                                         __HIP_MEMORY_SCOPE_AGENT);
        float qmn = __uint_as_float(mnu);
        float qmx = __uint_as_float(mxu);
        float step = __fmul_rn(__fsub_rn(qmx, qmn), 0.03125f);
        if (step <= 0.f) step = 1.f;

        // quantize in-register -> pack 4 indices/word -> LDS stage
#pragma unroll
        for (int uh = 0; uh < 2; ++uh)
#pragma unroll
            for (int u = 0; u < 4; ++u) {
                int rr = uh * 64 + (ty << 2) + u;
#pragma unroll
                for (int vh = 0; vh < 2; ++vh) {
                    float ix;
                    unsigned pack;
                    ix = fminf(fmaxf(floorf(__fdiv_rn(__fsub_rn(acc[uh * 4 + u][vh * 4 + 0], qmn), step)), 0.f), 31.f);
                    pack = (unsigned)(int)ix;
                    ix = fminf(fmaxf(floorf(__fdiv_rn(__fsub_rn(acc[uh * 4 + u][vh * 4 + 1], qmn), step)), 0.f), 31.f);
                    pack |= (unsigned)(int)ix << 8;
                    ix = fminf(fmaxf(floorf(__fdiv_rn(__fsub_rn(acc[uh * 4 + u][vh * 4 + 2], qmn), step)), 0.f), 31.f);
                    pack |= (unsigned)(int)ix << 16;
                    ix = fminf(fmaxf(floorf(__fdiv_rn(__fsub_rn(acc[uh * 4 + u][vh * 4 + 3], qmn), step)), 0.f), 31.f);
                    pack |= (unsigned)(int)ix << 24;
                    stage[rr * 33 + vh * 16 + tx] = pack;
                }
            }
        __syncthreads();

        // tile-major contiguous write: private 16KB tile, consecutive
        // threads -> consecutive 16B (4KB contiguous per wave instr x 4).
        {
            unsigned char* tbase = Pidx +
                ((size_t)(((s * 8 + i) * 16 + colgrp) * 8 + btile)) * 16384;
#pragma unroll
            for (int rep = 0; rep < 4; ++rep) {
                int j = rep * 256 + tid;          // 16B-quad index 0..1023
                int rr = j >> 3, c4 = (j & 7) << 2;
                const unsigned* sp = &stage[rr * 33 + c4];
                uint4 v = make_uint4(sp[0], sp[1], sp[2], sp[3]);
                *(uint4*)&tbase[(size_t)j * 16] = v;
            }
        }
        __syncthreads();   // stage/Bs safe to rewrite next plane
    }
}

// fold1: reconstruct pq = idx*step + mn (exact same fp32 ops as before) and
// run the full original chain. Block per b, 512 threads.
// Pidx element (s,i,b,f,kk): tile = ((s*8+i)*16 + kk*4 + (f>>7))*8 + (b>>7);
// byte = tile*16384 + (b&127)*128 + (f&127).
__global__ void fold1_kernel(const unsigned char* __restrict__ Pidx,
                             const unsigned* __restrict__ stats,
                             const float* __restrict__ Dq1, const float* __restrict__ sx1,
                             float* __restrict__ xq2, unsigned* __restrict__ xqb2,
                             float* __restrict__ sx2)
{
    __shared__ float red[512];
    __shared__ float dt;
    __shared__ float2 st[224];
    int b = blockIdx.x;
    int f = threadIdx.x;                      // 0..511
    if (f < 224) {
        float mn = __uint_as_float(stats[f * 2]);
        float mx = __uint_as_float(stats[f * 2 + 1]);
        float step = __fmul_rn(__fsub_rn(mx, mn), 0.03125f);
        if (step <= 0.f) step = 1.f;
        st[f] = make_float2(mn, step);
    }
    if (f == 0) {
        float sd = 0.f;
        for (int i = 0; i < 8; ++i) {
            float sc = (float)(85 << i);
            for (int ss = 0; ss < 7; ++ss) sd = fmaf(Dq1[(i * 7 + ss) * 1024 + b], sc, sd);
        }
        dt = sd;
    }
    __syncthreads();
    const int fhi = f >> 7, fl = f & 127;
    const unsigned char* pb = Pidx + (size_t)(b >> 7) * 16384
                                   + (size_t)(b & 127) * 128 + fl;
    float accR = 0.f;
    for (int s = 0; s < 7; ++s) {
        float sum = 0.f;
        for (int i = 0; i < 8; ++i) {
            const int si16 = (s * 8 + i) * 16;
#pragma unroll
            for (int kk = 0; kk < 4; ++kk) {
                float2 ms = st[((s * 8 + i) << 2) + kk];
                float ixv = (float)pb[(size_t)(si16 + kk * 4 + fhi) * 131072];
                float pq = __fadd_rn(__fmul_rn(ixv, ms.y), ms.x);
                sum = fmaf(pq, (float)(1 << (i + 2 * kk)), sum);
            }
        }
        accR = __fadd_rn(accR, sum);
    }
    float total = __fsub_rn(accR, dt);
    float acc = __fdiv_rn(total, 0.9f);
    float o = __fsub_rn(__fdiv_rn(__fmul_rn(2.f, acc), 65025.f), __fdiv_rn(sx1[b], 255.f));
    float h = tanhf(o);
    h = fminf(fmaxf(h, 0.f), 1.f);
    float code = rintf(__fmul_rn(h, 255.f));
    xq2[b * 512 + f] = code;
    int ci = (int)code;
    int lane = f & 63;
#pragma unroll
    for (int i = 0; i < 8; ++i) {
        unsigned long long m = __ballot((ci >> i) & 1);
        if ((lane & 31) == 0) {
            unsigned wv = (lane & 32) ? (unsigned)(m >> 32) : (unsigned)m;
            xqb2[(i * 1024 + b) * 16 + (f >> 5)] = wv;
        }
    }
    red[f] = code;
    __syncthreads();
    for (int w = 256; w >= 1; w >>= 1) {
        if (f < w) red[f] += red[f + w];
        __syncthreads();
    }
    if (f == 0) sx2[b] = red[0];
}

// Layer-2 matmul: thread per (s,b,f), 32 accumulators (i,k)
__global__ void mm2_kernel(const float* __restrict__ xq2, const float* __restrict__ g2t,
                           float* __restrict__ P2)
{
    int gid = blockIdx.x * 256 + threadIdx.x;  // 40960
    if (gid >= 40960) return;
    int f = gid % 10;
    int b = (gid / 10) & 1023;
    int s = gid / 10240;
    float acc[8][4] = {};
    for (int a = 0; a < 128; ++a) {
        int n = s * 128 + a;
        int xi = (int)xq2[b * 512 + n];
        float g0 = g2t[n * 40 + f];
        float gA = g2t[n * 40 + 10 + f];
        float gB = g2t[n * 40 + 20 + f];
        float gC = g2t[n * 40 + 30 + f];
#pragma unroll
        for (int i = 0; i < 8; ++i) {
            float bi = (float)((xi >> i) & 1);
            acc[i][0] = fmaf(bi, g0, acc[i][0]);
            acc[i][1] = fmaf(bi, gA, acc[i][1]);
            acc[i][2] = fmaf(bi, gB, acc[i][2]);
            acc[i][3] = fmaf(bi, gC, acc[i][3]);
        }
    }
#pragma unroll
    for (int i = 0; i < 8; ++i)
#pragma unroll
        for (int k = 0; k < 4; ++k)
            P2[(size_t)((s * 8 + i) * 4 + k) * 10240 + b * 10 + f] = acc[i][k];
}

__global__ void stat2_kernel(const float* __restrict__ P2, float2* __restrict__ stats2)
{
    __shared__ float red[512];
    int p = blockIdx.x;  // 128 planes
    int tid = threadIdx.x;
    float mn = FLTMAX, mx = -FLTMAX;
    for (int t = tid; t < 10240; t += 256) {
        float v = P2[(size_t)p * 10240 + t];
        mn = fminf(mn, v); mx = fmaxf(mx, v);
    }
    red[tid] = mn; red[256 + tid] = mx;
    __syncthreads();
    for (int w = 128; w >= 1; w >>= 1) {
        if (tid < w) {
            red[tid] = fminf(red[tid], red[tid + w]);
            red[256 + tid] = fmaxf(red[256 + tid], red[256 + tid + w]);
        }
        __syncthreads();
    }
    if (tid == 0) {
        float step = __fmul_rn(__fsub_rn(red[256], red[0]), 0.03125f);
        if (step <= 0.f) step = 1.f;
        stats2[p] = make_float2(red[0], step);
    }
}

// dterm2[b] computed inline per thread (exact i-outer/s-inner chain).
__global__ void out2_kernel(const float* __restrict__ P2, const float2* __restrict__ stats2,
                            const float* __restrict__ Dq2, const float* __restrict__ sx2,
                            float* __restrict__ out)
{
    int gid = blockIdx.x * 256 + threadIdx.x;  // 10240
    if (gid >= 10240) return;
    int b = gid / 10;
    float dt = 0.f;
    for (int i = 0; i < 8; ++i) {
        float sc = (float)(85 << i);
        for (int s = 0; s < 4; ++s) dt = fmaf(Dq2[(i * 4 + s) * 1024 + b], sc, dt);
    }
    float sum = 0.f;
    for (int s = 0; s < 4; ++s)
        for (int i = 0; i < 8; ++i)
#pragma unroll
            for (int k = 0; k < 4; ++k) {
                int p = (s * 8 + i) * 4 + k;
                float2 st = stats2[p];
                float val = P2[(size_t)p * 10240 + gid];
                float idx = fminf(fmaxf(floorf(__fdiv_rn(__fsub_rn(val, st.x), st.y)), 0.f), 31.f);
                float pq = __fadd_rn(__fmul_rn(idx, st.y), st.x);
                sum = fmaf(pq, (float)(1 << (i + 2 * k)), sum);
            }
    float total = __fsub_rn(sum, dt);
    float acc = __fdiv_rn(total, 0.9f);
    out[gid] = __fsub_rn(__fdiv_rn(__fmul_rn(2.f, acc), 65025.f), __fdiv_rn(sx2[b], 255.f));
}

extern "C" void kernel_launch(void* const* d_in, const int* in_sizes, int n_in,
                              void* d_out, int out_size, void* d_ws, size_t ws_size,
                              hipStream_t stream)
{
    const float* x      = (const float*)d_in[0];
    const float* w1     = (const float*)d_in[1];
    const float* w3     = (const float*)d_in[2];
    const float* noise1 = (const float*)d_in[3];
    const float* noise3 = (const float*)d_in[4];
    float* out = (float*)d_out;
    float* ws  = (float*)d_ws;

    // ws layout (float offsets)
    float*         g1t    = ws + 0;              // 896*2048
    float*         xq2    = ws + 1835008;        // 1024*512
    float*         P2     = ws + 2359296;        // 128*10240
    float*         g2t    = ws + 3670016;        // 512*40
    float*         Dq1    = ws + 3690496;        // 56*1024
    float*         Dq2    = ws + 3747840;        // 32*1024
    float*         sx1    = ws + 3780608;        // 1024
    float*         sx2    = ws + 3781632;        // 1024
    float2*        stats2 = (float2*)(ws + 3782656);    // 128 pairs
    unsigned*      stats1 = (unsigned*)(ws + 3782912);  // 224*2 words
    unsigned*      xqbT   = (unsigned*)(ws + 3783424);  // 8*28*1024 words
    unsigned*      xqb2   = (unsigned*)(ws + 4012800);  // 8*1024*16 words
    unsigned char* Pidx   = (unsigned char*)(ws + 4143872);  // 7168 tiles * 16KB
    unsigned*      bar    = (unsigned*)(ws + 33504256); // 3584 words (after Pidx)

    prep1_kernel<<<1024, 128, 0, stream>>>(x, sx1, xqbT, stats1, bar);
    prepg1t_kernel<<<dim3(28, 16), 256, 0, stream>>>(w1, noise1, g1t);
    dqpopT_kernel<<<56, 256, 0, stream>>>(xqbT, Dq1);

    mm1_kernel<<<1024, 256, 0, stream>>>(xqbT, g1t, Pidx, stats1, bar);

    fold1_kernel<<<1024, 512, 0, stream>>>(Pidx, stats1, Dq1, sx1, xq2, xqb2, sx2);
    prepg2_kernel<<<20, 256, 0, stream>>>(w3, noise3, g2t);
    dqpop_kernel<<<32, 256, 0, stream>>>(xqb2, Dq2, 4, 16);
    mm2_kernel<<<160, 256, 0, stream>>>(xq2, g2t, P2);
    stat2_kernel<<<128, 256, 0, stream>>>(P2, stats2);
    out2_kernel<<<40, 256, 0, stream>>>(P2, stats2, Dq2, sx2, out);
}

// Round 13
// 633.300 us; speedup vs baseline: 1.0765x; 1.0765x over previous
//
#include <hip/hip_runtime.h>

#define FLTMAX 3.402823466e+38f

// ---------------------------------------------------------------------------
// Geometry:
//   Layer1: B=1024, N=784, Np=896, S=7, F=512, I=8, K=4
//   Layer2: B=1024, N=512, Np=512, S=4, F=10,  I=8, K=4
// Layer-1: persistent-grid kernel, 1024 blocks x 256 threads, ONE 128x128
// tile per block (R0 geometry). Residency target: 4 blocks/CU —
//   LDS 34.8KB x 4 = 139KB <= 160KB; VGPR 128 x 4 waves/SIMD = 512 = file.
//
// R12 post-mortem (the allocator matrix):
//   cap 128 (launch_bounds(256,4) OR waves_per_eu(4,4)) -> picks 64 + SPILLS
//   cap 256 (launch_bounds(256,2))                      -> picks 128, NO spill
// R8/R9 proved (256,2)->128-reg allocation; their 2-blocks/CU limit was the
// 53.7KB two-tile LDS, not VGPR. R13 = R12's one-tile 34.8KB geometry +
// (256,2). launch_bounds' 2nd arg is an allocation hint only — the runtime
// schedules by actual resources: VGPR 128 allows 4 waves/SIMD, so 4 blocks/CU
// co-resident -> all 1024 blocks resident (barrier-safe; bounded spin fails
// visibly, never hangs, if not).
//
// Ordering chain (R5-R12, passed): tid0 issues device-scope atomicMin/Max
// on stats; s_waitcnt vmcnt(0) drains them to the coherence point; THEN
// arrival fetch_add on the slot counter. Waiters spin (RELAXED AGENT) and
// read stats with RELAXED AGENT loads — both at the coherence point past
// the non-coherent per-XCD L2. No fences (R3: fences = L2 flush storms).
// Pidx layout (R7): tile-major, tile = ((s*8+i)*16+colgrp)*8+btile, 16KB
// contiguous per tile; LDS-staged 16B stores (R5). fold1 unchanged.
// ---------------------------------------------------------------------------

// slotbar: 224 counters, one per (s*8+i)*4+k, 64B apart (16 words).
__device__ __forceinline__ void slot_barrier(unsigned* ctr, unsigned target)
{
    __syncthreads();
    if (threadIdx.x == 0) {
        // drain this wave's outstanding VMEM (incl. the stats atomics) so
        // they are complete at the coherence point before we signal.
        asm volatile("s_waitcnt vmcnt(0)" ::: "memory");
        __hip_atomic_fetch_add(ctr, 1u, __ATOMIC_RELAXED, __HIP_MEMORY_SCOPE_AGENT);
        // bounded spin (fails visibly, never hangs): healthy wait << 50us
        for (int it = 0; it < (1 << 22); ++it) {
            if (__hip_atomic_load(ctr, __ATOMIC_RELAXED, __HIP_MEMORY_SCOPE_AGENT) >= target)
                break;
            __builtin_amdgcn_s_sleep(2);
        }
    }
    __syncthreads();
}

// Fused: xq codes (row in LDS) -> sx1 row sum + bit-packed planes xqbT[i][w][b].
// Also initializes stats1 + slot-barrier counters.
__global__ void prep1_kernel(const float* __restrict__ x, float* __restrict__ sx1,
                             unsigned* __restrict__ xqbT, unsigned* __restrict__ stats1,
                             unsigned* __restrict__ bar)
{
    __shared__ float xr[896];
    __shared__ float red[128];
    int b = blockIdx.x;
    if (b == 0) {
        for (int t = threadIdx.x; t < 224; t += 128) {
            stats1[t * 2] = 0x7F7FFFFFu; stats1[t * 2 + 1] = 0u;
        }
        for (int t = threadIdx.x; t < 3584; t += 128) bar[t] = 0u;
    }
    float psum = 0.f;
    for (int n = threadIdx.x; n < 896; n += 128) {
        float v = 0.f;
        if (n < 784) {
            float xv = x[b * 784 + n];
            xv = fminf(fmaxf(xv, 0.f), 1.f);
            v = rintf(__fmul_rn(xv, 255.f));
        }
        xr[n] = v;
        psum += v;  // integer-valued, exact in any order
    }
    red[threadIdx.x] = psum;
    __syncthreads();
    for (int w = 64; w >= 1; w >>= 1) {
        if (threadIdx.x < w) red[threadIdx.x] += red[threadIdx.x + w];
        __syncthreads();
    }
    if (threadIdx.x == 0) sx1[b] = red[0];
    if (threadIdx.x < 28) {
        int w = threadIdx.x;
        unsigned words[8] = {0, 0, 0, 0, 0, 0, 0, 0};
#pragma unroll 8
        for (int n = 0; n < 32; ++n) {
            int v = (int)xr[w * 32 + n];
#pragma unroll
            for (int i = 0; i < 8; ++i) words[i] |= ((unsigned)((v >> i) & 1)) << n;
        }
#pragma unroll
        for (int i = 0; i < 8; ++i) xqbT[(i * 28 + w) * 1024 + b] = words[i];
    }
}

// Fused conductance-prep + transpose: writes g1t[n][k*512+f] directly.
__global__ void prepg1t_kernel(const float* __restrict__ w1, const float* __restrict__ noise1,
                               float* __restrict__ g1t)
{
    __shared__ float t[4][32][33];
    const int n0 = blockIdx.x * 32, f0 = blockIdx.y * 32;
    const int tid = threadIdx.x;
    {
        int n = tid & 31, fi = tid >> 5;
#pragma unroll
        for (int p = 0; p < 4; ++p) {
            int f = p * 8 + fi;
            int gn = n0 + n, gf = f0 + f;
            float gv[4] = {0.f, 0.f, 0.f, 0.f};
            if (gn < 784) {
                float w = w1[gf * 784 + gn];
                float Xi = fminf(fmaxf(rintf(__fmul_rn(__fmul_rn(__fadd_rn(w, 1.f), 0.5f), 255.f)),
                                       0.f), 255.f);
                int xi = (int)Xi;
                float4 nz = *(const float4*)&noise1[(gf * 896 + gn) * 4];
                float nzv[4] = {nz.x, nz.y, nz.z, nz.w};
#pragma unroll
                for (int k = 0; k < 4; ++k) {
                    int slc = (xi >> (2 * k)) & 3;
                    float base = __fadd_rn(__fmul_rn((float)slc, 0.9f), 0.3f);
                    float nf = __fadd_rn(1.f, __fmul_rn(0.05f, nzv[k]));
                    gv[k] = __fmul_rn(base, nf);
                }
            }
#pragma unroll
            for (int k = 0; k < 4; ++k) t[k][n][f] = gv[k];
        }
    }
    __syncthreads();
    {
        int f = tid & 31, nn = tid >> 5;
#pragma unroll
        for (int p = 0; p < 4; ++p) {
            int n = p * 8 + nn;
#pragma unroll
            for (int k = 0; k < 4; ++k)
                g1t[(n0 + n) * 2048 + k * 512 + f0 + f] = t[k][n][f];
        }
    }
}

// g2t[n][k][f] layout for layer-2 matmul
__global__ void prepg2_kernel(const float* __restrict__ w3, const float* __restrict__ noise3,
                              float* __restrict__ g2t)
{
    int gid = blockIdx.x * 256 + threadIdx.x;
    if (gid >= 10 * 512) return;
    int f = gid / 512, n = gid % 512;
    float w = w3[f * 512 + n];
    float Xi = fminf(fmaxf(rintf(__fmul_rn(__fmul_rn(__fadd_rn(w, 1.f), 0.5f), 255.f)),
                           0.f), 255.f);
    int xi = (int)Xi;
#pragma unroll
    for (int k = 0; k < 4; ++k) {
        int slc = (xi >> (2 * k)) & 3;
        float base = __fadd_rn(__fmul_rn((float)slc, 0.9f), 0.3f);
        float nf = __fadd_rn(1.f, __fmul_rn(0.05f, noise3[(f * 512 + n) * 4 + k]));
        g2t[n * 40 + k * 10 + f] = __fmul_rn(base, nf);
    }
}

// Layer-1 dummy column from transposed bit-planes: D = 0.3*popc(128 bits).
__global__ void dqpopT_kernel(const unsigned* __restrict__ xqbT, float* __restrict__ Dq)
{
    __shared__ float red[512];
    const int i = blockIdx.x / 7, s = blockIdx.x % 7;
    const int tid = threadIdx.x;
    float D[4];
    float mn = FLTMAX, mx = -FLTMAX;
#pragma unroll
    for (int u = 0; u < 4; ++u) {
        int b = tid + u * 256;
        int c = 0;
#pragma unroll
        for (int w = 0; w < 4; ++w)
            c += __popc(xqbT[(i * 28 + s * 4 + w) * 1024 + b]);
        D[u] = __fmul_rn((float)c, 0.3f);
        mn = fminf(mn, D[u]);
        mx = fmaxf(mx, D[u]);
    }
    red[tid] = mn; red[256 + tid] = mx;
    __syncthreads();
    for (int w = 128; w >= 1; w >>= 1) {
        if (tid < w) {
            red[tid] = fminf(red[tid], red[tid + w]);
            red[256 + tid] = fmaxf(red[256 + tid], red[256 + tid + w]);
        }
        __syncthreads();
    }
    mn = red[0]; mx = red[256];
    float step = __fmul_rn(__fsub_rn(mx, mn), 0.03125f);
    if (step <= 0.f) step = 1.f;
#pragma unroll
    for (int u = 0; u < 4; ++u) {
        int b = tid + u * 256;
        float idx = fminf(fmaxf(floorf(__fdiv_rn(__fsub_rn(D[u], mn), step)), 0.f), 31.f);
        Dq[(i * 7 + s) * 1024 + b] = __fadd_rn(__fmul_rn(idx, step), mn);
    }
}

// Layer-2 dummy column from xqb2 ([i][b][16w] layout).
__global__ void dqpop_kernel(const unsigned* __restrict__ xqb, float* __restrict__ Dq,
                             int S, int wpr)
{
    __shared__ float red[512];
    const int i = blockIdx.x / S, s = blockIdx.x % S;
    const int tid = threadIdx.x;
    float D[4];
    float mn = FLTMAX, mx = -FLTMAX;
#pragma unroll
    for (int u = 0; u < 4; ++u) {
        int b = tid + u * 256;
        uint4 w = *(const uint4*)&xqb[(i * 1024 + b) * wpr + s * 4];
        int c = __popc(w.x) + __popc(w.y) + __popc(w.z) + __popc(w.w);
        D[u] = __fmul_rn((float)c, 0.3f);
        mn = fminf(mn, D[u]);
        mx = fmaxf(mx, D[u]);
    }
    red[tid] = mn; red[256 + tid] = mx;
    __syncthreads();
    for (int w = 128; w >= 1; w >>= 1) {
        if (tid < w) {
            red[tid] = fminf(red[tid], red[tid + w]);
            red[256 + tid] = fmaxf(red[256 + tid], red[256 + tid + w]);
        }
        __syncthreads();
    }
    mn = red[0]; mx = red[256];
    float step = __fmul_rn(__fsub_rn(mx, mn), 0.03125f);
    if (step <= 0.f) step = 1.f;
#pragma unroll
    for (int u = 0; u < 4; ++u) {
        int b = tid + u * 256;
        float idx = fminf(fmaxf(floorf(__fdiv_rn(__fsub_rn(D[u], mn), step)), 0.f), 31.f);
        Dq[(i * S + s) * 1024 + b] = __fadd_rn(__fmul_rn(idx, step), mn);
    }
}

// ---------------------------------------------------------------------------
// Layer-1 persistent GEMM: 1024 blocks x 256 threads, 4 blocks/CU target.
// One 128x128 tile per block (R0 geometry); scalar acc[8][8]; wave-shfl
// min/max; per-slot 32-block sync; within-plane prefetch only; tile-major
// Pidx with 16KB contiguous burst per block-plane.
// launch_bounds(256,2): cap-256 register budget — the ONLY config where the
// allocator reliably picks 128 and does NOT spill acc (R8/R9 evidence).
// ---------------------------------------------------------------------------
#define BK 32
__global__ __launch_bounds__(256, 2) void mm1_kernel(
    const unsigned* __restrict__ xqbT, const float* __restrict__ g1t,
    unsigned char* __restrict__ Pidx, unsigned* stats, unsigned* bar)
{
    __shared__ __align__(16) float Bs[BK][132];
    __shared__ unsigned Abits[128];
    __shared__ float redmn[4], redmx[4];
    __shared__ __align__(16) unsigned stage[128 * 33];
    const int tid = threadIdx.x;
    const int r = blockIdx.x & 63;
    const int i = r >> 3;
    const int btile = r & 7;
    const int b0 = btile * 128;
    const int colgrp = blockIdx.x >> 6;      // 0..15
    const int colBase = colgrp * 128;
    const int tx = tid & 15, ty = tid >> 4;
    const int aB = tid >> 5;          // 0..7  (B rows: u*8 + aB)
    const int eB = (tid & 31) << 2;   // 0..124
    const int k = colgrp >> 2;
    const int wv = tid >> 6, ln = tid & 63;

    for (int s = 0; s < 7; ++s) {
        // prefetch chunk 0  (xqbT layout: [i][w][b], w = s*4 + chunk)
        float4 pB[4];
        unsigned pAw = 0;
#pragma unroll
        for (int u = 0; u < 4; ++u)
            pB[u] = *(const float4*)&g1t[(s * 128 + u * 8 + aB) * 2048 + colBase + eB];
        if (tid < 128) pAw = xqbT[(i * 28 + s * 4) * 1024 + b0 + tid];

        float acc[8][8] = {};

        for (int ac = 0; ac < 4; ++ac) {
            __syncthreads();
#pragma unroll
            for (int u = 0; u < 4; ++u)
                *(float4*)&Bs[u * 8 + aB][eB] = pB[u];
            if (tid < 128) Abits[tid] = pAw;
            __syncthreads();

            if (ac < 3) {
                const int n0 = s * 128 + (ac + 1) * BK;
#pragma unroll
                for (int u = 0; u < 4; ++u)
                    pB[u] = *(const float4*)&g1t[(n0 + u * 8 + aB) * 2048 + colBase + eB];
                if (tid < 128) pAw = xqbT[(i * 28 + s * 4 + ac + 1) * 1024 + b0 + tid];
            }

            unsigned wrd[8];
#pragma unroll
            for (int u = 0; u < 4; ++u) {
                wrd[u]     = Abits[(ty << 2) + u];
                wrd[4 + u] = Abits[64 + (ty << 2) + u];
            }

#pragma unroll 4
            for (int a = 0; a < BK; ++a) {
                float br[8];
                *(float4*)&br[0] = *(const float4*)&Bs[a][(tx << 2)];
                *(float4*)&br[4] = *(const float4*)&Bs[a][64 + (tx << 2)];
#pragma unroll
                for (int u = 0; u < 8; ++u) {
                    float ab = (float)((wrd[u] >> a) & 1u);
#pragma unroll
                    for (int v = 0; v < 8; ++v)
                        acc[u][v] = fmaf(ab, br[v], acc[u][v]);
                }
            }
        }

        // min/max: wave shfl butterfly (no syncthreads), then one
        // cross-wave step. Order-independent -> bit-safe.
        float mn = acc[0][0], mx = acc[0][0];
#pragma unroll
        for (int u = 0; u < 8; ++u)
#pragma unroll
            for (int v = 0; v < 8; ++v) {
                mn = fminf(mn, acc[u][v]); mx = fmaxf(mx, acc[u][v]);
            }
#pragma unroll
        for (int o = 32; o >= 1; o >>= 1) {
            mn = fminf(mn, __shfl_xor(mn, o));
            mx = fmaxf(mx, __shfl_xor(mx, o));
        }
        if (ln == 0) { redmn[wv] = mn; redmx[wv] = mx; }
        __syncthreads();
        const int slot = ((s * 8 + i) * 4 + k);
        if (tid == 0) {
            float m0 = fminf(fminf(redmn[0], redmn[1]), fminf(redmn[2], redmn[3]));
            float m1 = fmaxf(fmaxf(redmx[0], redmx[1]), fmaxf(redmx[2], redmx[3]));
            atomicMin(&stats[slot * 2],     __float_as_uint(m0));
            atomicMax(&stats[slot * 2 + 1], __float_as_uint(m1));
        }

        // per-slot sync: the 32 blocks sharing (s,i,k) rendezvous.
        slot_barrier(&bar[slot * 16], 32u);

        // COHERENT read at the atomics' coherence point.
        unsigned mnu = __hip_atomic_load(&stats[slot * 2],     __ATOMIC_RELAXED,
                                         __HIP_MEMORY_SCOPE_AGENT);
        unsigned mxu = __hip_atomic_load(&stats[slot * 2 + 1], __ATOMIC_RELAXED,
                                         __HIP_MEMORY_SCOPE_AGENT);
        float qmn = __uint_as_float(mnu);
        float qmx = __uint_as_float(mxu);
        float step = __fmul_rn(__fsub_rn(qmx, qmn), 0.03125f);
        if (step <= 0.f) step = 1.f;

        // quantize in-register -> pack 4 indices/word -> LDS stage
#pragma unroll
        for (int uh = 0; uh < 2; ++uh)
#pragma unroll
            for (int u = 0; u < 4; ++u) {
                int rr = uh * 64 + (ty << 2) + u;
#pragma unroll
                for (int vh = 0; vh < 2; ++vh) {
                    float ix;
                    unsigned pack;
                    ix = fminf(fmaxf(floorf(__fdiv_rn(__fsub_rn(acc[uh * 4 + u][vh * 4 + 0], qmn), step)), 0.f), 31.f);
                    pack = (unsigned)(int)ix;
                    ix = fminf(fmaxf(floorf(__fdiv_rn(__fsub_rn(acc[uh * 4 + u][vh * 4 + 1], qmn), step)), 0.f), 31.f);
                    pack |= (unsigned)(int)ix << 8;
                    ix = fminf(fmaxf(floorf(__fdiv_rn(__fsub_rn(acc[uh * 4 + u][vh * 4 + 2], qmn), step)), 0.f), 31.f);
                    pack |= (unsigned)(int)ix << 16;
                    ix = fminf(fmaxf(floorf(__fdiv_rn(__fsub_rn(acc[uh * 4 + u][vh * 4 + 3], qmn), step)), 0.f), 31.f);
                    pack |= (unsigned)(int)ix << 24;
                    stage[rr * 33 + vh * 16 + tx] = pack;
                }
            }
        __syncthreads();

        // tile-major contiguous write: private 16KB tile, consecutive
        // threads -> consecutive 16B (4KB contiguous per wave instr x 4).
        {
            unsigned char* tbase = Pidx +
                ((size_t)(((s * 8 + i) * 16 + colgrp) * 8 + btile)) * 16384;
#pragma unroll
            for (int rep = 0; rep < 4; ++rep) {
                int j = rep * 256 + tid;          // 16B-quad index 0..1023
                int rr = j >> 3, c4 = (j & 7) << 2;
                const unsigned* sp = &stage[rr * 33 + c4];
                uint4 v = make_uint4(sp[0], sp[1], sp[2], sp[3]);
                *(uint4*)&tbase[(size_t)j * 16] = v;
            }
        }
        __syncthreads();   // stage/Bs safe to rewrite next plane
    }
}

// fold1: reconstruct pq = idx*step + mn (exact same fp32 ops as before) and
// run the full original chain. Block per b, 512 threads.
// Pidx element (s,i,b,f,kk): tile = ((s*8+i)*16 + kk*4 + (f>>7))*8 + (b>>7);
// byte = tile*16384 + (b&127)*128 + (f&127).
__global__ void fold1_kernel(const unsigned char* __restrict__ Pidx,
                             const unsigned* __restrict__ stats,
                             const float* __restrict__ Dq1, const float* __restrict__ sx1,
                             float* __restrict__ xq2, unsigned* __restrict__ xqb2,
                             float* __restrict__ sx2)
{
    __shared__ float red[512];
    __shared__ float dt;
    __shared__ float2 st[224];
    int b = blockIdx.x;
    int f = threadIdx.x;                      // 0..511
    if (f < 224) {
        float mn = __uint_as_float(stats[f * 2]);
        float mx = __uint_as_float(stats[f * 2 + 1]);
        float step = __fmul_rn(__fsub_rn(mx, mn), 0.03125f);
        if (step <= 0.f) step = 1.f;
        st[f] = make_float2(mn, step);
    }
    if (f == 0) {
        float sd = 0.f;
        for (int i = 0; i < 8; ++i) {
            float sc = (float)(85 << i);
            for (int ss = 0; ss < 7; ++ss) sd = fmaf(Dq1[(i * 7 + ss) * 1024 + b], sc, sd);
        }
        dt = sd;
    }
    __syncthreads();
    const int fhi = f >> 7, fl = f & 127;
    const unsigned char* pb = Pidx + (size_t)(b >> 7) * 16384
                                   + (size_t)(b & 127) * 128 + fl;
    float accR = 0.f;
    for (int s = 0; s < 7; ++s) {
        float sum = 0.f;
        for (int i = 0; i < 8; ++i) {
            const int si16 = (s * 8 + i) * 16;
#pragma unroll
            for (int kk = 0; kk < 4; ++kk) {
                float2 ms = st[((s * 8 + i) << 2) + kk];
                float ixv = (float)pb[(size_t)(si16 + kk * 4 + fhi) * 131072];
                float pq = __fadd_rn(__fmul_rn(ixv, ms.y), ms.x);
                sum = fmaf(pq, (float)(1 << (i + 2 * kk)), sum);
            }
        }
        accR = __fadd_rn(accR, sum);
    }
    float total = __fsub_rn(accR, dt);
    float acc = __fdiv_rn(total, 0.9f);
    float o = __fsub_rn(__fdiv_rn(__fmul_rn(2.f, acc), 65025.f), __fdiv_rn(sx1[b], 255.f));
    float h = tanhf(o);
    h = fminf(fmaxf(h, 0.f), 1.f);
    float code = rintf(__fmul_rn(h, 255.f));
    xq2[b * 512 + f] = code;
    int ci = (int)code;
    int lane = f & 63;
#pragma unroll
    for (int i = 0; i < 8; ++i) {
        unsigned long long m = __ballot((ci >> i) & 1);
        if ((lane & 31) == 0) {
            unsigned wv = (lane & 32) ? (unsigned)(m >> 32) : (unsigned)m;
            xqb2[(i * 1024 + b) * 16 + (f >> 5)] = wv;
        }
    }
    red[f] = code;
    __syncthreads();
    for (int w = 256; w >= 1; w >>= 1) {
        if (f < w) red[f] += red[f + w];
        __syncthreads();
    }
    if (f == 0) sx2[b] = red[0];
}

// Layer-2 matmul: thread per (s,b,f), 32 accumulators (i,k)
__global__ void mm2_kernel(const float* __restrict__ xq2, const float* __restrict__ g2t,
                           float* __restrict__ P2)
{
    int gid = blockIdx.x * 256 + threadIdx.x;  // 40960
    if (gid >= 40960) return;
    int f = gid % 10;
    int b = (gid / 10) & 1023;
    int s = gid / 10240;
    float acc[8][4] = {};
    for (int a = 0; a < 128; ++a) {
        int n = s * 128 + a;
        int xi = (int)xq2[b * 512 + n];
        float g0 = g2t[n * 40 + f];
        float gA = g2t[n * 40 + 10 + f];
        float gB = g2t[n * 40 + 20 + f];
        float gC = g2t[n * 40 + 30 + f];
#pragma unroll
        for (int i = 0; i < 8; ++i) {
            float bi = (float)((xi >> i) & 1);
            acc[i][0] = fmaf(bi, g0, acc[i][0]);
            acc[i][1] = fmaf(bi, gA, acc[i][1]);
            acc[i][2] = fmaf(bi, gB, acc[i][2]);
            acc[i][3] = fmaf(bi, gC, acc[i][3]);
        }
    }
#pragma unroll
    for (int i = 0; i < 8; ++i)
#pragma unroll
        for (int k = 0; k < 4; ++k)
            P2[(size_t)((s * 8 + i) * 4 + k) * 10240 + b * 10 + f] = acc[i][k];
}

__global__ void stat2_kernel(const float* __restrict__ P2, float2* __restrict__ stats2)
{
    __shared__ float red[512];
    int p = blockIdx.x;  // 128 planes
    int tid = threadIdx.x;
    float mn = FLTMAX, mx = -FLTMAX;
    for (int t = tid; t < 10240; t += 256) {
        float v = P2[(size_t)p * 10240 + t];
        mn = fminf(mn, v); mx = fmaxf(mx, v);
    }
    red[tid] = mn; red[256 + tid] = mx;
    __syncthreads();
    for (int w = 128; w >= 1; w >>= 1) {
        if (tid < w) {
            red[tid] = fminf(red[tid], red[tid + w]);
            red[256 + tid] = fmaxf(red[256 + tid], red[256 + tid + w]);
        }
        __syncthreads();
    }
    if (tid == 0) {
        float step = __fmul_rn(__fsub_rn(red[256], red[0]), 0.03125f);
        if (step <= 0.f) step = 1.f;
        stats2[p] = make_float2(red[0], step);
    }
}

// dterm2[b] computed inline per thread (exact i-outer/s-inner chain).
__global__ void out2_kernel(const float* __restrict__ P2, const float2* __restrict__ stats2,
                            const float* __restrict__ Dq2, const float* __restrict__ sx2,
                            float* __restrict__ out)
{
    int gid = blockIdx.x * 256 + threadIdx.x;  // 10240
    if (gid >= 10240) return;
    int b = gid / 10;
    float dt = 0.f;
    for (int i = 0; i < 8; ++i) {
        float sc = (float)(85 << i);
        for (int s = 0; s < 4; ++s) dt = fmaf(Dq2[(i * 4 + s) * 1024 + b], sc, dt);
    }
    float sum = 0.f;
    for (int s = 0; s < 4; ++s)
        for (int i = 0; i < 8; ++i)
#pragma unroll
            for (int k = 0; k < 4; ++k) {
                int p = (s * 8 + i) * 4 + k;
                float2 st = stats2[p];
                float val = P2[(size_t)p * 10240 + gid];
                float idx = fminf(fmaxf(floorf(__fdiv_rn(__fsub_rn(val, st.x), st.y)), 0.f), 31.f);
                float pq = __fadd_rn(__fmul_rn(idx, st.y), st.x);
                sum = fmaf(pq, (float)(1 << (i + 2 * k)), sum);
            }
    float total = __fsub_rn(sum, dt);
    float acc = __fdiv_rn(total, 0.9f);
    out[gid] = __fsub_rn(__fdiv_rn(__fmul_rn(2.f, acc), 65025.f), __fdiv_rn(sx2[b], 255.f));
}

extern "C" void kernel_launch(void* const* d_in, const int* in_sizes, int n_in,
                              void* d_out, int out_size, void* d_ws, size_t ws_size,
                              hipStream_t stream)
{
    const float* x      = (const float*)d_in[0];
    const float* w1     = (const float*)d_in[1];
    const float* w3     = (const float*)d_in[2];
    const float* noise1 = (const float*)d_in[3];
    const float* noise3 = (const float*)d_in[4];
    float* out = (float*)d_out;
    float* ws  = (float*)d_ws;

    // ws layout (float offsets)
    float*         g1t    = ws + 0;              // 896*2048
    float*         xq2    = ws + 1835008;        // 1024*512
    float*         P2     = ws + 2359296;        // 128*10240
    float*         g2t    = ws + 3670016;        // 512*40
    float*         Dq1    = ws + 3690496;        // 56*1024
    float*         Dq2    = ws + 3747840;        // 32*1024
    float*         sx1    = ws + 3780608;        // 1024
    float*         sx2    = ws + 3781632;        // 1024
    float2*        stats2 = (float2*)(ws + 3782656);    // 128 pairs
    unsigned*      stats1 = (unsigned*)(ws + 3782912);  // 224*2 words
    unsigned*      xqbT   = (unsigned*)(ws + 3783424);  // 8*28*1024 words
    unsigned*      xqb2   = (unsigned*)(ws + 4012800);  // 8*1024*16 words
    unsigned char* Pidx   = (unsigned char*)(ws + 4143872);  // 7168 tiles * 16KB
    unsigned*      bar    = (unsigned*)(ws + 33504256); // 3584 words (after Pidx)

    prep1_kernel<<<1024, 128, 0, stream>>>(x, sx1, xqbT, stats1, bar);
    prepg1t_kernel<<<dim3(28, 16), 256, 0, stream>>>(w1, noise1, g1t);
    dqpopT_kernel<<<56, 256, 0, stream>>>(xqbT, Dq1);

    mm1_kernel<<<1024, 256, 0, stream>>>(xqbT, g1t, Pidx, stats1, bar);

    fold1_kernel<<<1024, 512, 0, stream>>>(Pidx, stats1, Dq1, sx1, xq2, xqb2, sx2);
    prepg2_kernel<<<20, 256, 0, stream>>>(w3, noise3, g2t);
    dqpop_kernel<<<32, 256, 0, stream>>>(xqb2, Dq2, 4, 16);
    mm2_kernel<<<160, 256, 0, stream>>>(xq2, g2t, P2);
    stat2_kernel<<<128, 256, 0, stream>>>(P2, stats2);
    out2_kernel<<<40, 256, 0, stream>>>(P2, stats2, Dq2, sx2, out);
}